// Round 1
// baseline (731.406 us; speedup 1.0000x reference)
//
#include <hip/hip_runtime.h>
#include <hip/hip_bf16.h>

#define FDIM 128

// ---- bf16 helpers (manual, RNE) ----
static __device__ __forceinline__ unsigned short f2bf(float x) {
    unsigned u = __float_as_uint(x);
    unsigned r = 0x7fffu + ((u >> 16) & 1u);
    return (unsigned short)((u + r) >> 16);
}
static __device__ __forceinline__ float bf_lo(unsigned u) {  // low bf16 of packed pair
    return __uint_as_float(u << 16);
}
static __device__ __forceinline__ float bf_hi(unsigned u) {  // high bf16
    return __uint_as_float(u & 0xffff0000u);
}

// ---- k0: Ws = W + W^T (fp32, 128x128 = 16384 elems) ----
__global__ void make_ws(const float* __restrict__ W, float* __restrict__ Ws) {
    int idx = blockIdx.x * blockDim.x + threadIdx.x;
    int i = idx >> 7, j = idx & 127;
    Ws[idx] = W[i * FDIM + j] + W[j * FDIM + i];
}

// ---- k1: Fbf = bf16(F), vectorized float4 -> 4x bf16 ----
__global__ void cvt_f(const float* __restrict__ Fm, unsigned short* __restrict__ Fbf,
                      int total4) {
    int idx = blockIdx.x * blockDim.x + threadIdx.x;
    if (idx < total4) {
        float4 v = ((const float4*)Fm)[idx];
        ushort4 o;
        o.x = f2bf(v.x); o.y = f2bf(v.y); o.z = f2bf(v.z); o.w = f2bf(v.w);
        ((ushort4*)Fbf)[idx] = o;
    }
}

// ---- k2: G = F @ Ws, output bf16. Ws symmetric so row/col read interchangeable.
// Block: 256 thr, 32 rows/block. LDS: Ws fp32 (64KB) + F tile (16KB) -> 2 blocks/CU.
// Each thread: 4 rows x 4 cols register tile.
__global__ __launch_bounds__(256, 2) void gemm_g(
    const float* __restrict__ Fm, const float* __restrict__ Ws,
    unsigned short* __restrict__ Gbf, int N) {
    __shared__ float sWs[FDIM * FDIM];   // 64 KB
    __shared__ float sF[32][FDIM];       // 16 KB

    for (int k = threadIdx.x; k < FDIM * FDIM / 4; k += 256)
        ((float4*)sWs)[k] = ((const float4*)Ws)[k];

    int row0 = blockIdx.x * 32;
    for (int k = threadIdx.x; k < 32 * FDIM / 4; k += 256) {
        int r = k >> 5, c = k & 31;
        int gr = row0 + r;
        float4 v = make_float4(0.f, 0.f, 0.f, 0.f);
        if (gr < N) v = ((const float4*)Fm)[(size_t)gr * (FDIM / 4) + c];
        ((float4*)&sF[r][0])[c] = v;
    }
    __syncthreads();

    int tx = threadIdx.x & 31;   // col group: cols 4*tx .. 4*tx+3
    int ty = threadIdx.x >> 5;   // row group: rows ty*4 .. ty*4+3
    int c0 = tx * 4;
    float acc[4][4] = {};

    for (int i = 0; i < FDIM; ++i) {
        float4 w = *(const float4*)&sWs[i * FDIM + c0];
        float f0 = sF[ty * 4 + 0][i];
        float f1 = sF[ty * 4 + 1][i];
        float f2 = sF[ty * 4 + 2][i];
        float f3 = sF[ty * 4 + 3][i];
        acc[0][0] = fmaf(f0, w.x, acc[0][0]);
        acc[0][1] = fmaf(f0, w.y, acc[0][1]);
        acc[0][2] = fmaf(f0, w.z, acc[0][2]);
        acc[0][3] = fmaf(f0, w.w, acc[0][3]);
        acc[1][0] = fmaf(f1, w.x, acc[1][0]);
        acc[1][1] = fmaf(f1, w.y, acc[1][1]);
        acc[1][2] = fmaf(f1, w.z, acc[1][2]);
        acc[1][3] = fmaf(f1, w.w, acc[1][3]);
        acc[2][0] = fmaf(f2, w.x, acc[2][0]);
        acc[2][1] = fmaf(f2, w.y, acc[2][1]);
        acc[2][2] = fmaf(f2, w.z, acc[2][2]);
        acc[2][3] = fmaf(f2, w.w, acc[2][3]);
        acc[3][0] = fmaf(f3, w.x, acc[3][0]);
        acc[3][1] = fmaf(f3, w.y, acc[3][1]);
        acc[3][2] = fmaf(f3, w.z, acc[3][2]);
        acc[3][3] = fmaf(f3, w.w, acc[3][3]);
    }

    for (int r = 0; r < 4; ++r) {
        int gr = row0 + ty * 4 + r;
        if (gr < N) {
            ushort4 o;
            o.x = f2bf(acc[r][0]); o.y = f2bf(acc[r][1]);
            o.z = f2bf(acc[r][2]); o.w = f2bf(acc[r][3]);
            *(ushort4*)(Gbf + (size_t)gr * FDIM + c0) = o;
        }
    }
}

// ---- k3: edge kernel. 16 lanes per edge, 16B/lane (8 bf16), 4 edges/wave.
// s = dot(Gbf[i0], Fbf[i1]); atomicAdd(out[mol], s).
__global__ __launch_bounds__(256) void edge_kernel(
    const unsigned short* __restrict__ Gbf, const unsigned short* __restrict__ Fbf,
    const int* __restrict__ idx, const int* __restrict__ mol,
    float* __restrict__ out, int E) {
    const int lane = threadIdx.x & 63;
    const int sub  = lane >> 4;     // which of 4 edges in this wave
    const int t16  = lane & 15;     // position within the edge's row
    const int wave_id = (blockIdx.x * blockDim.x + threadIdx.x) >> 6;
    const int nwaves  = (gridDim.x * blockDim.x) >> 6;

    for (int base = wave_id * 4; base < E; base += nwaves * 4) {
        int e = base + sub;
        float p = 0.f;
        int m = 0;
        bool valid = (e < E);
        if (valid) {
            int i0 = idx[e];
            int i1 = idx[E + e];
            m = mol[e];
            const uint4 g = *(const uint4*)(Gbf + (size_t)i0 * FDIM + t16 * 8);
            const uint4 f = *(const uint4*)(Fbf + (size_t)i1 * FDIM + t16 * 8);
            p  = bf_lo(g.x) * bf_lo(f.x);
            p  = fmaf(bf_hi(g.x), bf_hi(f.x), p);
            p  = fmaf(bf_lo(g.y), bf_lo(f.y), p);
            p  = fmaf(bf_hi(g.y), bf_hi(f.y), p);
            p  = fmaf(bf_lo(g.z), bf_lo(f.z), p);
            p  = fmaf(bf_hi(g.z), bf_hi(f.z), p);
            p  = fmaf(bf_lo(g.w), bf_lo(f.w), p);
            p  = fmaf(bf_hi(g.w), bf_hi(f.w), p);
        }
        // reduce across the 16 lanes of this edge
        p += __shfl_xor(p, 1, 16);
        p += __shfl_xor(p, 2, 16);
        p += __shfl_xor(p, 4, 16);
        p += __shfl_xor(p, 8, 16);
        if (t16 == 0 && valid) atomicAdd(out + m, p);
    }
}

extern "C" void kernel_launch(void* const* d_in, const int* in_sizes, int n_in,
                              void* d_out, int out_size, void* d_ws, size_t ws_size,
                              hipStream_t stream) {
    const float* Fm = (const float*)d_in[0];
    const float* W  = (const float*)d_in[1];
    const int* idx  = (const int*)d_in[2];
    const int* mol  = (const int*)d_in[3];
    float* out = (float*)d_out;

    const int N = in_sizes[0] / FDIM;   // 50000
    const int E = in_sizes[3];          // 1600000

    // workspace layout: Ws fp32 (64KB) | Fbf (N*128 bf16) | Gbf (N*128 bf16)
    char* ws = (char*)d_ws;
    float* Ws = (float*)ws;
    size_t off = 65536;
    unsigned short* Fbf = (unsigned short*)(ws + off);
    size_t fb = ((size_t)N * FDIM * 2 + 255) & ~(size_t)255;
    unsigned short* Gbf = (unsigned short*)(ws + off + fb);

    hipMemsetAsync(d_out, 0, (size_t)out_size * sizeof(float), stream);

    make_ws<<<FDIM * FDIM / 256, 256, 0, stream>>>(W, Ws);

    int total4 = N * FDIM / 4;
    cvt_f<<<(total4 + 255) / 256, 256, 0, stream>>>(Fm, Fbf, total4);

    gemm_g<<<(N + 31) / 32, 256, 0, stream>>>(Fm, Ws, Gbf, N);

    edge_kernel<<<2048, 256, 0, stream>>>(Gbf, Fbf, idx, mol, out, E);
}

// Round 2
// 727.200 us; speedup vs baseline: 1.0058x; 1.0058x over previous
//
#include <hip/hip_runtime.h>
#include <hip/hip_bf16.h>

#define FDIM 128

// ---- bf16 helpers (manual, RNE) ----
static __device__ __forceinline__ unsigned short f2bf(float x) {
    unsigned u = __float_as_uint(x);
    unsigned r = 0x7fffu + ((u >> 16) & 1u);
    return (unsigned short)((u + r) >> 16);
}
static __device__ __forceinline__ float bf_lo(unsigned u) { return __uint_as_float(u << 16); }
static __device__ __forceinline__ float bf_hi(unsigned u) { return __uint_as_float(u & 0xffff0000u); }

// ---- k0: Ws = W + W^T (fp32, 128x128) ----
__global__ void make_ws(const float* __restrict__ W, float* __restrict__ Ws) {
    int idx = blockIdx.x * blockDim.x + threadIdx.x;
    int i = idx >> 7, j = idx & 127;
    Ws[idx] = W[i * FDIM + j] + W[j * FDIM + i];
}

// ---- k1: G = F @ Ws (bf16 out) AND Fbf = bf16(F) emitted from the staged LDS tile.
// Block: 256 thr, 32 rows/block. LDS: Ws fp32 (64KB) + F tile (16KB) -> 2 blocks/CU.
__global__ __launch_bounds__(256, 2) void gemm_g(
    const float* __restrict__ Fm, const float* __restrict__ Ws,
    unsigned short* __restrict__ Gbf, unsigned short* __restrict__ Fbf, int N) {
    __shared__ float sWs[FDIM * FDIM];   // 64 KB
    __shared__ float sF[32][FDIM];       // 16 KB

    for (int k = threadIdx.x; k < FDIM * FDIM / 4; k += 256)
        ((float4*)sWs)[k] = ((const float4*)Ws)[k];

    int row0 = blockIdx.x * 32;
    for (int k = threadIdx.x; k < 32 * FDIM / 4; k += 256) {
        int r = k >> 5, c = k & 31;
        int gr = row0 + r;
        float4 v = make_float4(0.f, 0.f, 0.f, 0.f);
        if (gr < N) v = ((const float4*)Fm)[(size_t)gr * (FDIM / 4) + c];
        ((float4*)&sF[r][0])[c] = v;
    }
    __syncthreads();

    // emit bf16 copy of F (reuses the LDS tile; kills the separate cvt pass)
    for (int k = threadIdx.x; k < 32 * FDIM / 4; k += 256) {
        int r = k >> 5, c = k & 31;
        int gr = row0 + r;
        if (gr < N) {
            float4 v = ((float4*)&sF[r][0])[c];
            ushort4 o;
            o.x = f2bf(v.x); o.y = f2bf(v.y); o.z = f2bf(v.z); o.w = f2bf(v.w);
            *(ushort4*)(Fbf + (size_t)gr * FDIM + c * 4) = o;
        }
    }

    int tx = threadIdx.x & 31;
    int ty = threadIdx.x >> 5;
    int c0 = tx * 4;
    float acc[4][4] = {};

    for (int i = 0; i < FDIM; ++i) {
        float4 w = *(const float4*)&sWs[i * FDIM + c0];
        float f0 = sF[ty * 4 + 0][i];
        float f1 = sF[ty * 4 + 1][i];
        float f2 = sF[ty * 4 + 2][i];
        float f3 = sF[ty * 4 + 3][i];
        acc[0][0] = fmaf(f0, w.x, acc[0][0]);
        acc[0][1] = fmaf(f0, w.y, acc[0][1]);
        acc[0][2] = fmaf(f0, w.z, acc[0][2]);
        acc[0][3] = fmaf(f0, w.w, acc[0][3]);
        acc[1][0] = fmaf(f1, w.x, acc[1][0]);
        acc[1][1] = fmaf(f1, w.y, acc[1][1]);
        acc[1][2] = fmaf(f1, w.z, acc[1][2]);
        acc[1][3] = fmaf(f1, w.w, acc[1][3]);
        acc[2][0] = fmaf(f2, w.x, acc[2][0]);
        acc[2][1] = fmaf(f2, w.y, acc[2][1]);
        acc[2][2] = fmaf(f2, w.z, acc[2][2]);
        acc[2][3] = fmaf(f2, w.w, acc[2][3]);
        acc[3][0] = fmaf(f3, w.x, acc[3][0]);
        acc[3][1] = fmaf(f3, w.y, acc[3][1]);
        acc[3][2] = fmaf(f3, w.z, acc[3][2]);
        acc[3][3] = fmaf(f3, w.w, acc[3][3]);
    }

    for (int r = 0; r < 4; ++r) {
        int gr = row0 + ty * 4 + r;
        if (gr < N) {
            ushort4 o;
            o.x = f2bf(acc[r][0]); o.y = f2bf(acc[r][1]);
            o.z = f2bf(acc[r][2]); o.w = f2bf(acc[r][3]);
            *(ushort4*)(Gbf + (size_t)gr * FDIM + c0) = o;
        }
    }
}

// ---- k2: edge kernel, 4x unrolled. 16 lanes/edge, 16 edges per wave-iteration.
// All index loads issued, then all 8 gathers, THEN consumption -> 8 outstanding
// gathers per wave instead of 2. __launch_bounds__(256,8) pins VGPR<=64 so
// occupancy stays 32 waves/CU.
__global__ __launch_bounds__(256, 8) void edge_kernel(
    const unsigned short* __restrict__ Gbf, const unsigned short* __restrict__ Fbf,
    const int* __restrict__ idx, const int* __restrict__ mol,
    float* __restrict__ out, int E) {
    const int lane = threadIdx.x & 63;
    const int sub  = lane >> 4;
    const int t16  = lane & 15;
    const int off16 = t16 * 8;
    const int wave_id = (blockIdx.x * blockDim.x + threadIdx.x) >> 6;
    const int nwaves  = (gridDim.x * blockDim.x) >> 6;

    for (int base = wave_id * 16; base < E; base += nwaves * 16) {
        int i0[4], i1[4], m[4];
        #pragma unroll
        for (int u = 0; u < 4; ++u) {
            int e = base + u * 4 + sub;
            int ec = (e < E) ? e : 0;
            i0[u] = idx[ec];
            i1[u] = idx[E + ec];
            m[u]  = mol[ec];
        }
        uint4 g[4], f[4];
        #pragma unroll
        for (int u = 0; u < 4; ++u) {
            g[u] = *(const uint4*)(Gbf + (size_t)i0[u] * FDIM + off16);
            f[u] = *(const uint4*)(Fbf + (size_t)i1[u] * FDIM + off16);
        }
        #pragma unroll
        for (int u = 0; u < 4; ++u) {
            float p;
            p = bf_lo(g[u].x) * bf_lo(f[u].x);
            p = fmaf(bf_hi(g[u].x), bf_hi(f[u].x), p);
            p = fmaf(bf_lo(g[u].y), bf_lo(f[u].y), p);
            p = fmaf(bf_hi(g[u].y), bf_hi(f[u].y), p);
            p = fmaf(bf_lo(g[u].z), bf_lo(f[u].z), p);
            p = fmaf(bf_hi(g[u].z), bf_hi(f[u].z), p);
            p = fmaf(bf_lo(g[u].w), bf_lo(f[u].w), p);
            p = fmaf(bf_hi(g[u].w), bf_hi(f[u].w), p);
            p += __shfl_xor(p, 1, 16);
            p += __shfl_xor(p, 2, 16);
            p += __shfl_xor(p, 4, 16);
            p += __shfl_xor(p, 8, 16);
            int e = base + u * 4 + sub;
            if (t16 == 0 && e < E) atomicAdd(out + m[u], p);
        }
    }
}

extern "C" void kernel_launch(void* const* d_in, const int* in_sizes, int n_in,
                              void* d_out, int out_size, void* d_ws, size_t ws_size,
                              hipStream_t stream) {
    const float* Fm = (const float*)d_in[0];
    const float* W  = (const float*)d_in[1];
    const int* idx  = (const int*)d_in[2];
    const int* mol  = (const int*)d_in[3];
    float* out = (float*)d_out;

    const int N = in_sizes[0] / FDIM;   // 50000
    const int E = in_sizes[3];          // 1600000

    char* ws = (char*)d_ws;
    float* Ws = (float*)ws;
    size_t off = 65536;
    unsigned short* Fbf = (unsigned short*)(ws + off);
    size_t fb = ((size_t)N * FDIM * 2 + 255) & ~(size_t)255;
    unsigned short* Gbf = (unsigned short*)(ws + off + fb);

    hipMemsetAsync(d_out, 0, (size_t)out_size * sizeof(float), stream);

    make_ws<<<FDIM * FDIM / 256, 256, 0, stream>>>(W, Ws);

    gemm_g<<<(N + 31) / 32, 256, 0, stream>>>(Fm, Ws, Gbf, Fbf, N);

    edge_kernel<<<2048, 256, 0, stream>>>(Gbf, Fbf, idx, mol, out, E);
}

// Round 3
// 320.019 us; speedup vs baseline: 2.2855x; 2.2724x over previous
//
#include <hip/hip_runtime.h>
#include <hip/hip_bf16.h>

#define FDIM 128
#define SB 64   // sort blocks for hist/scatter passes

// ---- bf16 helpers (manual, RNE) ----
static __device__ __forceinline__ unsigned short f2bf(float x) {
    unsigned u = __float_as_uint(x);
    unsigned r = 0x7fffu + ((u >> 16) & 1u);
    return (unsigned short)((u + r) >> 16);
}
static __device__ __forceinline__ float bf_lo(unsigned u) { return __uint_as_float(u << 16); }
static __device__ __forceinline__ float bf_hi(unsigned u) { return __uint_as_float(u & 0xffff0000u); }

// ---- k0: Ws = W + W^T ----
__global__ void make_ws(const float* __restrict__ W, float* __restrict__ Ws) {
    int idx = blockIdx.x * blockDim.x + threadIdx.x;
    int i = idx >> 7, j = idx & 127;
    Ws[idx] = W[i * FDIM + j] + W[j * FDIM + i];
}

// ---- k1: G = F @ Ws (bf16 out) AND Fbf = bf16(F) emitted from the staged tile ----
__global__ __launch_bounds__(256, 2) void gemm_g(
    const float* __restrict__ Fm, const float* __restrict__ Ws,
    unsigned short* __restrict__ Gbf, unsigned short* __restrict__ Fbf, int N) {
    __shared__ float sWs[FDIM * FDIM];
    __shared__ float sF[32][FDIM];

    for (int k = threadIdx.x; k < FDIM * FDIM / 4; k += 256)
        ((float4*)sWs)[k] = ((const float4*)Ws)[k];

    int row0 = blockIdx.x * 32;
    for (int k = threadIdx.x; k < 32 * FDIM / 4; k += 256) {
        int r = k >> 5, c = k & 31;
        int gr = row0 + r;
        float4 v = make_float4(0.f, 0.f, 0.f, 0.f);
        if (gr < N) v = ((const float4*)Fm)[(size_t)gr * (FDIM / 4) + c];
        ((float4*)&sF[r][0])[c] = v;
    }
    __syncthreads();

    for (int k = threadIdx.x; k < 32 * FDIM / 4; k += 256) {
        int r = k >> 5, c = k & 31;
        int gr = row0 + r;
        if (gr < N) {
            float4 v = ((float4*)&sF[r][0])[c];
            ushort4 o;
            o.x = f2bf(v.x); o.y = f2bf(v.y); o.z = f2bf(v.z); o.w = f2bf(v.w);
            *(ushort4*)(Fbf + (size_t)gr * FDIM + c * 4) = o;
        }
    }

    int tx = threadIdx.x & 31;
    int ty = threadIdx.x >> 5;
    int c0 = tx * 4;
    float acc[4][4] = {};

    for (int i = 0; i < FDIM; ++i) {
        float4 w = *(const float4*)&sWs[i * FDIM + c0];
        float f0 = sF[ty * 4 + 0][i];
        float f1 = sF[ty * 4 + 1][i];
        float f2 = sF[ty * 4 + 2][i];
        float f3 = sF[ty * 4 + 3][i];
        acc[0][0] = fmaf(f0, w.x, acc[0][0]); acc[0][1] = fmaf(f0, w.y, acc[0][1]);
        acc[0][2] = fmaf(f0, w.z, acc[0][2]); acc[0][3] = fmaf(f0, w.w, acc[0][3]);
        acc[1][0] = fmaf(f1, w.x, acc[1][0]); acc[1][1] = fmaf(f1, w.y, acc[1][1]);
        acc[1][2] = fmaf(f1, w.z, acc[1][2]); acc[1][3] = fmaf(f1, w.w, acc[1][3]);
        acc[2][0] = fmaf(f2, w.x, acc[2][0]); acc[2][1] = fmaf(f2, w.y, acc[2][1]);
        acc[2][2] = fmaf(f2, w.z, acc[2][2]); acc[2][3] = fmaf(f2, w.w, acc[2][3]);
        acc[3][0] = fmaf(f3, w.x, acc[3][0]); acc[3][1] = fmaf(f3, w.y, acc[3][1]);
        acc[3][2] = fmaf(f3, w.z, acc[3][2]); acc[3][3] = fmaf(f3, w.w, acc[3][3]);
    }

    for (int r = 0; r < 4; ++r) {
        int gr = row0 + ty * 4 + r;
        if (gr < N) {
            ushort4 o;
            o.x = f2bf(acc[r][0]); o.y = f2bf(acc[r][1]);
            o.z = f2bf(acc[r][2]); o.w = f2bf(acc[r][3]);
            *(ushort4*)(Gbf + (size_t)gr * FDIM + c0) = o;
        }
    }
}

// ---- k2: histogram of i1 buckets. SB blocks, per-block LDS counters -> M[b*SB+blk] ----
__global__ __launch_bounds__(256) void k_hist(const int* __restrict__ idx, int E,
                                              int brows, int nb, unsigned* __restrict__ M) {
    extern __shared__ unsigned cnt[];
    for (int k = threadIdx.x; k < nb; k += 256) cnt[k] = 0;
    __syncthreads();
    int chunk = (E + SB - 1) / SB;
    int s = blockIdx.x * chunk;
    int e_end = min(E, s + chunk);
    for (int e = s + threadIdx.x; e < e_end; e += 256) {
        int i1 = idx[E + e];
        atomicAdd(&cnt[i1 / brows], 1u);
    }
    __syncthreads();
    for (int k = threadIdx.x; k < nb; k += 256) M[(size_t)k * SB + blockIdx.x] = cnt[k];
}

// ---- k3a: per-256-block exclusive scan; write block totals to P ----
__global__ __launch_bounds__(256) void k_scan1(unsigned* __restrict__ M, unsigned* __restrict__ P) {
    __shared__ unsigned wsum[5];
    int t = threadIdx.x, lane = t & 63, wid = t >> 6;
    int idx = blockIdx.x * 256 + t;
    unsigned v = M[idx];
    unsigned incl = v;
    for (int d = 1; d < 64; d <<= 1) {
        unsigned u = __shfl_up(incl, d, 64);
        if (lane >= d) incl += u;
    }
    if (lane == 63) wsum[wid] = incl;
    __syncthreads();
    if (t == 0) {
        unsigned a = 0;
        for (int i = 0; i < 4; ++i) { unsigned x = wsum[i]; wsum[i] = a; a += x; }
        wsum[4] = a;
    }
    __syncthreads();
    unsigned excl = incl - v + wsum[wid];
    M[idx] = excl;
    if (t == 255) P[blockIdx.x] = wsum[4];
}

// ---- k3b: scan P (n <= 512) in one block ----
__global__ __launch_bounds__(256) void k_scan2(unsigned* __restrict__ P, int n) {
    __shared__ unsigned A[512], B[512];
    int t = threadIdx.x;
    unsigned o0 = (t < n) ? P[t] : 0;
    unsigned o1 = (t + 256 < n) ? P[t + 256] : 0;
    A[t] = o0; A[t + 256] = o1;
    __syncthreads();
    unsigned *src = A, *dst = B;
    for (int d = 1; d < 512; d <<= 1) {
        dst[t] = src[t] + ((t >= d) ? src[t - d] : 0u);
        int j = t + 256;
        dst[j] = src[j] + ((j >= d) ? src[j - d] : 0u);
        __syncthreads();
        unsigned* tmp = src; src = dst; dst = tmp;
    }
    if (t < n) P[t] = src[t] - o0;
    if (t + 256 < n) P[t + 256] = src[t + 256] - o1;
}

// ---- k3c: add block offsets; emit bucketStart ----
__global__ __launch_bounds__(256) void k_scan3(unsigned* __restrict__ M, const unsigned* __restrict__ P,
                                               unsigned* __restrict__ bucketStart) {
    int idx = blockIdx.x * 256 + threadIdx.x;
    unsigned val = M[idx] + P[blockIdx.x];
    M[idx] = val;
    if ((idx & (SB - 1)) == 0) bucketStart[idx / SB] = val;
}

// ---- k4: scatter edges to sorted positions, packed u32 = i0 | mol<<16 | i1loc<<26 ----
__global__ __launch_bounds__(256) void k_scatter(const int* __restrict__ idx, const int* __restrict__ mol,
                                                 int E, int brows, int nb,
                                                 const unsigned* __restrict__ M,
                                                 unsigned* __restrict__ sortedE) {
    extern __shared__ unsigned cnt[];
    for (int k = threadIdx.x; k < nb; k += 256) cnt[k] = 0;
    __syncthreads();
    int chunk = (E + SB - 1) / SB;
    int s = blockIdx.x * chunk;
    int e_end = min(E, s + chunk);
    for (int e = s + threadIdx.x; e < e_end; e += 256) {
        int i0 = idx[e];
        int i1 = idx[E + e];
        int m  = mol[e];
        int b  = i1 / brows;
        int loc = i1 - b * brows;
        unsigned r = atomicAdd(&cnt[b], 1u);
        unsigned pos = M[(size_t)b * SB + blockIdx.x] + r;
        sortedE[pos] = (unsigned)i0 | ((unsigned)m << 16) | ((unsigned)loc << 26);
    }
}

// ---- k5: edge kernel. One WG per i1-bucket: F window in LDS, gather only G. ----
__global__ __launch_bounds__(256) void edge_kernel(
    const unsigned short* __restrict__ Gbf, const unsigned short* __restrict__ Fbf,
    const unsigned* __restrict__ sortedE, const unsigned* __restrict__ bucketStart,
    float* __restrict__ part, int E, int brows, int nb, int N) {
    __shared__ unsigned short sFrow[32 * FDIM];   // up to 32 rows * 256B = 8KB

    int b = blockIdx.x;
    int row0 = b * brows;
    int nrow = min(brows, N - row0);
    for (int k = threadIdx.x; k < nrow * (FDIM / 8); k += 256)
        ((uint4*)sFrow)[k] = ((const uint4*)(Fbf + (size_t)row0 * FDIM))[k];
    __syncthreads();

    int s = bucketStart[b];
    int e_end = (b == nb - 1) ? E : (int)bucketStart[b + 1];

    const int lane = threadIdx.x & 63;
    const int sub  = lane >> 4;
    const int t16  = lane & 15;
    const int wid  = threadIdx.x >> 6;
    float* pout = part + ((b & 31) << 10);

    for (int base = s + wid * 4; base < e_end; base += 16) {
        int e = base + sub;
        bool valid = (e < e_end);
        unsigned pk = valid ? sortedE[e] : 0u;
        int i0  = pk & 0xffff;
        int m   = (pk >> 16) & 0x3ff;
        int loc = pk >> 26;
        const uint4 g = *(const uint4*)(Gbf + (size_t)i0 * FDIM + t16 * 8);
        const uint4 f = *(const uint4*)(sFrow + loc * FDIM + t16 * 8);
        float p;
        p = bf_lo(g.x) * bf_lo(f.x);
        p = fmaf(bf_hi(g.x), bf_hi(f.x), p);
        p = fmaf(bf_lo(g.y), bf_lo(f.y), p);
        p = fmaf(bf_hi(g.y), bf_hi(f.y), p);
        p = fmaf(bf_lo(g.z), bf_lo(f.z), p);
        p = fmaf(bf_hi(g.z), bf_hi(f.z), p);
        p = fmaf(bf_lo(g.w), bf_lo(f.w), p);
        p = fmaf(bf_hi(g.w), bf_hi(f.w), p);
        p += __shfl_xor(p, 1, 16);
        p += __shfl_xor(p, 2, 16);
        p += __shfl_xor(p, 4, 16);
        p += __shfl_xor(p, 8, 16);
        if (t16 == 0 && valid) atomicAdd(pout + m, p);
    }
}

// ---- k6: reduce 32 partial copies -> out ----
__global__ __launch_bounds__(256) void k_red(const float* __restrict__ part,
                                             float* __restrict__ out, int M) {
    int m = blockIdx.x * 256 + threadIdx.x;
    if (m < M) {
        float s = 0.f;
        for (int c = 0; c < 32; ++c) s += part[(c << 10) + m];
        out[m] = s;
    }
}

extern "C" void kernel_launch(void* const* d_in, const int* in_sizes, int n_in,
                              void* d_out, int out_size, void* d_ws, size_t ws_size,
                              hipStream_t stream) {
    const float* Fm = (const float*)d_in[0];
    const float* W  = (const float*)d_in[1];
    const int* idx  = (const int*)d_in[2];
    const int* mol  = (const int*)d_in[3];
    float* out = (float*)d_out;

    const int N = in_sizes[0] / FDIM;   // 50000
    const int E = in_sizes[3];          // 1600000

    const int brows = (N + 1999) / 2000;       // 25 rows per bucket
    const int nb    = (N + brows - 1) / brows; // 2000 buckets
    const int T     = nb * SB;                 // scan matrix entries (128000)
    const int nScan = (T + 255) / 256;         // 500

    // workspace layout
    char* ws = (char*)d_ws;
    size_t o = 0;
    float* Ws = (float*)(ws + o);            o += 64 * 1024;
    unsigned short* Fbf = (unsigned short*)(ws + o); o += ((size_t)N * FDIM * 2 + 255) & ~(size_t)255;
    unsigned short* Gbf = (unsigned short*)(ws + o); o += ((size_t)N * FDIM * 2 + 255) & ~(size_t)255;
    unsigned* sortedE = (unsigned*)(ws + o); o += ((size_t)E * 4 + 255) & ~(size_t)255;
    unsigned* M = (unsigned*)(ws + o);       o += ((size_t)nScan * 256 * 4 + 255) & ~(size_t)255;
    unsigned* P = (unsigned*)(ws + o);       o += 4096;
    unsigned* bucketStart = (unsigned*)(ws + o); o += ((size_t)(nb + 1) * 4 + 255) & ~(size_t)255;
    float* part = (float*)(ws + o);          o += 32 * 1024 * sizeof(float);

    hipMemsetAsync(part, 0, 32 * 1024 * sizeof(float), stream);

    make_ws<<<FDIM * FDIM / 256, 256, 0, stream>>>(W, Ws);
    gemm_g<<<(N + 31) / 32, 256, 0, stream>>>(Fm, Ws, Gbf, Fbf, N);

    size_t smem = (size_t)nb * 4;
    k_hist<<<SB, 256, smem, stream>>>(idx, E, brows, nb, M);
    k_scan1<<<nScan, 256, 0, stream>>>(M, P);
    k_scan2<<<1, 256, 0, stream>>>(P, nScan);
    k_scan3<<<nScan, 256, 0, stream>>>(M, P, bucketStart);
    k_scatter<<<SB, 256, smem, stream>>>(idx, mol, E, brows, nb, M, sortedE);

    edge_kernel<<<nb, 256, 0, stream>>>(Gbf, Fbf, sortedE, bucketStart, part, E, brows, nb, N);

    k_red<<<(out_size + 255) / 256, 256, 0, stream>>>(part, out, out_size);
}